// Round 1
// baseline (6368.491 us; speedup 1.0000x reference)
//
#include <hip/hip_runtime.h>

// Shapes (fixed by the reference)
#define BN 4        // batch
#define CN 64       // C_IN
#define ON 64       // C_OUT
#define VN 163842   // vertices
#define KN 7        // kernel taps
#define JN 7        // interp outputs
#define CJ 448      // CN * JN
#define GROUP 8     // vertices per block-iteration
#define NGROUPS ((VN + GROUP - 1) / GROUP)   // 20481
#define GRID 512    // 2 blocks/CU * 256 CUs

// out[b,o,v] = sum_{c,j} ( sum_k x[b,c,idx[v,k]] * itp[v,k,j] ) * w[o,c,0,j] + bias[o]
//
// Thread roles:
//  phase A (T build):  c = t&63, b = t>>6
//  main GEMM:          o = t&63, cq = t>>6 (cq owns c in [cq*16, cq*16+16))
// T layout in LDS: Tl[vi][cj][b]  (b contiguous -> one uniform ds_read_b128 per (vi,cj))
// conv_w in registers: wreg[112] = w[o][cq*16 .. cq*16+15][0..6] (contiguous 112 floats)

__launch_bounds__(256, 2)
__global__ void sphere_conv_kernel(const float* __restrict__ x,
                                   const int* __restrict__ index,
                                   const float* __restrict__ itp,
                                   const float* __restrict__ w,
                                   const float* __restrict__ bias,
                                   float* __restrict__ out) {
    __shared__ float Tl[GROUP][CJ][4];          // 57,344 B
    float* red = &Tl[0][0][0];                  // reduction scratch aliases Tl: [4][64][36] = 36,864 B

    const int t  = threadIdx.x;
    const int o  = t & 63;
    const int cq = t >> 6;

    // --- one-time: conv_w slice into registers (contiguous 112 floats per thread) ---
    float wreg[112];
    {
        const float4* wp = reinterpret_cast<const float4*>(w + o * CJ + cq * 112);
        #pragma unroll
        for (int i = 0; i < 28; ++i) {
            float4 f = wp[i];
            wreg[i*4+0] = f.x; wreg[i*4+1] = f.y; wreg[i*4+2] = f.z; wreg[i*4+3] = f.w;
        }
    }

    const int cA = t & 63;   // phase-A channel
    const int bA = t >> 6;   // phase-A batch

    for (int g = blockIdx.x; g < NGROUPS; g += gridDim.x) {
        const int vbase = g * GROUP;

        // ---------- phase A: build T for 8 vertices ----------
        for (int vi = 0; vi < GROUP; ++vi) {
            const int v = min(vbase + vi, VN - 1);      // clamp loads; stores masked later
            const int*   ip = index + v * KN;
            const float* mp = itp   + v * KN * JN;
            float xv[KN];
            #pragma unroll
            for (int k = 0; k < KN; ++k) {
                const int ik = ip[k];                   // uniform -> s_load
                xv[k] = x[(size_t)(bA * CN + cA) * VN + ik];
            }
            #pragma unroll
            for (int j = 0; j < JN; ++j) {
                float tj = 0.f;
                #pragma unroll
                for (int k = 0; k < KN; ++k) tj = fmaf(xv[k], mp[k * JN + j], tj);
                Tl[vi][cA * JN + j][bA] = tj;
            }
        }
        __syncthreads();

        // ---------- main contraction: acc[v][b] over this thread's 112 cj ----------
        float acc[GROUP][4];
        #pragma unroll
        for (int vi = 0; vi < GROUP; ++vi) {
            acc[vi][0] = 0.f; acc[vi][1] = 0.f; acc[vi][2] = 0.f; acc[vi][3] = 0.f;
        }
        #pragma unroll
        for (int e = 0; e < 112; ++e) {
            const int cj = cq * 112 + e;                // static offset from runtime uniform base
            const float wv = wreg[e];                   // static index -> stays in VGPR
            #pragma unroll
            for (int vi = 0; vi < GROUP; ++vi) {
                const float4 tv = *reinterpret_cast<const float4*>(&Tl[vi][cj][0]);
                acc[vi][0] = fmaf(tv.x, wv, acc[vi][0]);
                acc[vi][1] = fmaf(tv.y, wv, acc[vi][1]);
                acc[vi][2] = fmaf(tv.z, wv, acc[vi][2]);
                acc[vi][3] = fmaf(tv.w, wv, acc[vi][3]);
            }
        }
        __syncthreads();

        // ---------- cross-cq reduction through LDS (aliases Tl) ----------
        #pragma unroll
        for (int vi = 0; vi < GROUP; ++vi) {
            float4 f;
            f.x = acc[vi][0]; f.y = acc[vi][1]; f.z = acc[vi][2]; f.w = acc[vi][3];
            *reinterpret_cast<float4*>(&red[(cq * 64 + o) * 36 + vi * 4]) = f;  // pad 36 (+16B aligned)
        }
        __syncthreads();

        // ---------- sum partials, add bias, coalesced-ish store (8-float v runs) ----------
        const int vloc = t & 7;
        #pragma unroll
        for (int p = 0; p < 8; ++p) {
            const int bo = (t >> 3) + p * 32;           // bo = b*64 + o, 0..255
            const int oo = bo & 63;
            const int bb = bo >> 6;
            float s = bias[oo];
            #pragma unroll
            for (int q = 0; q < 4; ++q)
                s += red[(q * 64 + oo) * 36 + vloc * 4 + bb];
            const int v = vbase + vloc;
            if (v < VN) out[(size_t)bo * VN + v] = s;
        }
        __syncthreads();   // protect Tl/red before next group's phase A
    }
}

extern "C" void kernel_launch(void* const* d_in, const int* in_sizes, int n_in,
                              void* d_out, int out_size, void* d_ws, size_t ws_size,
                              hipStream_t stream) {
    const float* x     = (const float*)d_in[0];   // (4, 64, 163842) f32
    const int*   index = (const int*)  d_in[1];   // (163842, 7) i32
    const float* itp   = (const float*)d_in[2];   // (163842, 7, 7) f32
    const float* w     = (const float*)d_in[3];   // (64, 64, 1, 7) f32
    const float* bias  = (const float*)d_in[4];   // (64,) f32
    float*       out   = (float*)d_out;           // (4, 64, 163842) f32

    sphere_conv_kernel<<<dim3(GRID), dim3(256), 0, stream>>>(x, index, itp, w, bias, out);
}

// Round 2
// 2772.014 us; speedup vs baseline: 2.2974x; 2.2974x over previous
//
#include <hip/hip_runtime.h>

// Shapes (fixed by the reference)
#define BN 4        // batch
#define CN 64       // C_IN
#define ON 64       // C_OUT
#define VN 163842   // vertices
#define KN 7        // kernel taps
#define JN 7        // interp outputs
#define CJ 448      // CN * JN
#define GROUP 8     // vertices per block-iteration
#define NGROUPS ((VN + GROUP - 1) / GROUP)   // 20481
#define GRID 512    // 2 blocks/CU * 256 CUs
#define VT_CHUNKS ((VN + 63) / 64)           // 2561

// ---------------------------------------------------------------------------
// Pass 1: transpose x[b][c][v] -> xT[b][v][c]  (makes the gather line-efficient)
// ---------------------------------------------------------------------------
__launch_bounds__(256, 4)
__global__ void transpose_kernel(const float* __restrict__ x, float* __restrict__ xT) {
    __shared__ float tile[64][65];              // +1 pad: conflict-free transpose
    const int bid   = blockIdx.x;
    const int b     = bid / VT_CHUNKS;
    const int vbase = (bid % VT_CHUNKS) * 64;
    const int t     = threadIdx.x;
    const int vl    = t & 63;
    const int cr    = t >> 6;                   // 0..3

    if (vbase + vl < VN) {
        #pragma unroll
        for (int i = 0; i < 16; ++i) {
            const int c = cr * 16 + i;
            tile[c][vl] = x[((size_t)b * CN + c) * VN + vbase + vl];   // coalesced 256B/wave
        }
    }
    __syncthreads();
    #pragma unroll
    for (int i = 0; i < 16; ++i) {
        const int vr = cr * 16 + i;
        const int v  = vbase + vr;
        if (v < VN)
            xT[((size_t)b * VN + v) * CN + (t & 63)] = tile[t & 63][vr]; // coalesced 256B/wave
    }
}

// ---------------------------------------------------------------------------
// Pass 2: main fused kernel, gathers from xT (contiguous 256B per (b,v,k))
// out[b,o,v] = sum_{c,j} ( sum_k xT[b,idx[v,k],c] * itp[v,k,j] ) * w[o,c,j] + bias[o]
// ---------------------------------------------------------------------------
__launch_bounds__(256, 2)
__global__ void sphere_conv_xt(const float* __restrict__ xT,
                               const int* __restrict__ index,
                               const float* __restrict__ itp,
                               const float* __restrict__ w,
                               const float* __restrict__ bias,
                               float* __restrict__ out) {
    __shared__ float Tl[GROUP][CJ][4];          // 57,344 B
    float* red = &Tl[0][0][0];                  // reduction scratch aliases Tl

    const int t  = threadIdx.x;
    const int o  = t & 63;
    const int cq = t >> 6;

    // conv_w slice in registers: w[o][cq*16 .. cq*16+15][0..6] (contiguous 112 floats)
    float wreg[112];
    {
        const float4* wp = reinterpret_cast<const float4*>(w + o * CJ + cq * 112);
        #pragma unroll
        for (int i = 0; i < 28; ++i) {
            float4 f = wp[i];
            wreg[i*4+0] = f.x; wreg[i*4+1] = f.y; wreg[i*4+2] = f.z; wreg[i*4+3] = f.w;
        }
    }

    const int cA = t & 63;   // phase-A channel (lane)
    const int bA = t >> 6;   // phase-A batch (wave)

    for (int g = blockIdx.x; g < NGROUPS; g += gridDim.x) {
        const int vbase = g * GROUP;

        // ---------- phase A: build T for 8 vertices (coalesced gathers) ----------
        for (int vi = 0; vi < GROUP; ++vi) {
            const int v = min(vbase + vi, VN - 1);
            const int*   ip = index + v * KN;
            const float* mp = itp   + v * KN * JN;
            float xv[KN];
            #pragma unroll
            for (int k = 0; k < KN; ++k) {
                const int ik = ip[k];                              // uniform per block
                xv[k] = xT[((size_t)bA * VN + ik) * CN + cA];      // 256B contiguous per wave
            }
            #pragma unroll
            for (int j = 0; j < JN; ++j) {
                float tj = 0.f;
                #pragma unroll
                for (int k = 0; k < KN; ++k) tj = fmaf(xv[k], mp[k * JN + j], tj);
                Tl[vi][cA * JN + j][bA] = tj;
            }
        }
        __syncthreads();

        // ---------- main contraction: acc[v][b] over this thread's 112 cj ----------
        float acc[GROUP][4];
        #pragma unroll
        for (int vi = 0; vi < GROUP; ++vi) {
            acc[vi][0] = 0.f; acc[vi][1] = 0.f; acc[vi][2] = 0.f; acc[vi][3] = 0.f;
        }
        #pragma unroll
        for (int e = 0; e < 112; ++e) {
            const int cj = cq * 112 + e;
            const float wv = wreg[e];
            #pragma unroll
            for (int vi = 0; vi < GROUP; ++vi) {
                const float4 tv = *reinterpret_cast<const float4*>(&Tl[vi][cj][0]);
                acc[vi][0] = fmaf(tv.x, wv, acc[vi][0]);
                acc[vi][1] = fmaf(tv.y, wv, acc[vi][1]);
                acc[vi][2] = fmaf(tv.z, wv, acc[vi][2]);
                acc[vi][3] = fmaf(tv.w, wv, acc[vi][3]);
            }
        }
        __syncthreads();

        // ---------- cross-cq reduction through LDS ----------
        #pragma unroll
        for (int vi = 0; vi < GROUP; ++vi) {
            float4 f;
            f.x = acc[vi][0]; f.y = acc[vi][1]; f.z = acc[vi][2]; f.w = acc[vi][3];
            *reinterpret_cast<float4*>(&red[(cq * 64 + o) * 36 + vi * 4]) = f;
        }
        __syncthreads();

        // ---------- sum partials, add bias, store ----------
        const int vloc = t & 7;
        #pragma unroll
        for (int p = 0; p < 8; ++p) {
            const int bo = (t >> 3) + p * 32;           // bo = b*64 + o
            const int oo = bo & 63;
            const int bb = bo >> 6;
            float s = bias[oo];
            #pragma unroll
            for (int q = 0; q < 4; ++q)
                s += red[(q * 64 + oo) * 36 + vloc * 4 + bb];
            const int v = vbase + vloc;
            if (v < VN) out[(size_t)bo * VN + v] = s;
        }
        __syncthreads();
    }
}

// ---------------------------------------------------------------------------
// Fallback (ws too small): the R1 kernel — direct strided gather from x.
// ---------------------------------------------------------------------------
__launch_bounds__(256, 2)
__global__ void sphere_conv_fallback(const float* __restrict__ x,
                                     const int* __restrict__ index,
                                     const float* __restrict__ itp,
                                     const float* __restrict__ w,
                                     const float* __restrict__ bias,
                                     float* __restrict__ out) {
    __shared__ float Tl[GROUP][CJ][4];
    float* red = &Tl[0][0][0];
    const int t  = threadIdx.x;
    const int o  = t & 63;
    const int cq = t >> 6;
    float wreg[112];
    {
        const float4* wp = reinterpret_cast<const float4*>(w + o * CJ + cq * 112);
        #pragma unroll
        for (int i = 0; i < 28; ++i) {
            float4 f = wp[i];
            wreg[i*4+0] = f.x; wreg[i*4+1] = f.y; wreg[i*4+2] = f.z; wreg[i*4+3] = f.w;
        }
    }
    const int cA = t & 63;
    const int bA = t >> 6;
    for (int g = blockIdx.x; g < NGROUPS; g += gridDim.x) {
        const int vbase = g * GROUP;
        for (int vi = 0; vi < GROUP; ++vi) {
            const int v = min(vbase + vi, VN - 1);
            const int*   ip = index + v * KN;
            const float* mp = itp   + v * KN * JN;
            float xv[KN];
            #pragma unroll
            for (int k = 0; k < KN; ++k) xv[k] = x[(size_t)(bA * CN + cA) * VN + ip[k]];
            #pragma unroll
            for (int j = 0; j < JN; ++j) {
                float tj = 0.f;
                #pragma unroll
                for (int k = 0; k < KN; ++k) tj = fmaf(xv[k], mp[k * JN + j], tj);
                Tl[vi][cA * JN + j][bA] = tj;
            }
        }
        __syncthreads();
        float acc[GROUP][4];
        #pragma unroll
        for (int vi = 0; vi < GROUP; ++vi) {
            acc[vi][0] = 0.f; acc[vi][1] = 0.f; acc[vi][2] = 0.f; acc[vi][3] = 0.f;
        }
        #pragma unroll
        for (int e = 0; e < 112; ++e) {
            const int cj = cq * 112 + e;
            const float wv = wreg[e];
            #pragma unroll
            for (int vi = 0; vi < GROUP; ++vi) {
                const float4 tv = *reinterpret_cast<const float4*>(&Tl[vi][cj][0]);
                acc[vi][0] = fmaf(tv.x, wv, acc[vi][0]);
                acc[vi][1] = fmaf(tv.y, wv, acc[vi][1]);
                acc[vi][2] = fmaf(tv.z, wv, acc[vi][2]);
                acc[vi][3] = fmaf(tv.w, wv, acc[vi][3]);
            }
        }
        __syncthreads();
        #pragma unroll
        for (int vi = 0; vi < GROUP; ++vi) {
            float4 f;
            f.x = acc[vi][0]; f.y = acc[vi][1]; f.z = acc[vi][2]; f.w = acc[vi][3];
            *reinterpret_cast<float4*>(&red[(cq * 64 + o) * 36 + vi * 4]) = f;
        }
        __syncthreads();
        const int vloc = t & 7;
        #pragma unroll
        for (int p = 0; p < 8; ++p) {
            const int bo = (t >> 3) + p * 32;
            const int oo = bo & 63;
            const int bb = bo >> 6;
            float s = bias[oo];
            #pragma unroll
            for (int q = 0; q < 4; ++q)
                s += red[(q * 64 + oo) * 36 + vloc * 4 + bb];
            const int v = vbase + vloc;
            if (v < VN) out[(size_t)bo * VN + v] = s;
        }
        __syncthreads();
    }
}

extern "C" void kernel_launch(void* const* d_in, const int* in_sizes, int n_in,
                              void* d_out, int out_size, void* d_ws, size_t ws_size,
                              hipStream_t stream) {
    const float* x     = (const float*)d_in[0];   // (4, 64, 163842) f32
    const int*   index = (const int*)  d_in[1];   // (163842, 7) i32
    const float* itp   = (const float*)d_in[2];   // (163842, 7, 7) f32
    const float* w     = (const float*)d_in[3];   // (64, 64, 1, 7) f32
    const float* bias  = (const float*)d_in[4];   // (64,) f32
    float*       out   = (float*)d_out;           // (4, 64, 163842) f32

    const size_t xt_bytes = (size_t)BN * VN * CN * sizeof(float);   // 167,774,208

    if (ws_size >= xt_bytes) {
        float* xT = (float*)d_ws;
        transpose_kernel<<<dim3(BN * VT_CHUNKS), dim3(256), 0, stream>>>(x, xT);
        sphere_conv_xt<<<dim3(GRID), dim3(256), 0, stream>>>(xT, index, itp, w, bias, out);
    } else {
        sphere_conv_fallback<<<dim3(GRID), dim3(256), 0, stream>>>(x, index, itp, w, bias, out);
    }
}